// Round 1
// baseline (203.295 us; speedup 1.0000x reference)
//
#include <hip/hip_runtime.h>
#include <math.h>

// ---------------------------------------------------------------------------
// AdaptiveFusionNet: dct_in = E x E^T (E = resize@idct@mask@dct, 8x256),
// grad_in = 4-point sobel sample, then tiny conv/bn/relu + fusion + classifier.
// ---------------------------------------------------------------------------

// Kernel 0: build E (8x256) in workspace.
// E[p,j] = sum_{k<25} F[p,k] * D[k,j],  F[p,k] = 0.5*(D[k,32p+15]+D[k,32p+16])
// D[k,n] = cos(pi*(2n+1)*k/512) * scale_k,  scale_0=sqrt(1/256), else sqrt(2/256)
__global__ __launch_bounds__(256) void k_compute_E(float* __restrict__ E) {
    __shared__ float F[8][25];
    const int tid = threadIdx.x;
    const float c0 = 3.14159265358979323846f / 512.0f;
    if (tid < 25) {
        const int k = tid;
        const float scale = (k == 0) ? sqrtf(1.0f / 256.0f) : sqrtf(2.0f / 256.0f);
        for (int p = 0; p < 8; ++p) {
            const int r0 = 32 * p + 15;
            const float a = cosf(c0 * (float)((2 * r0 + 1) * k));
            const float b = cosf(c0 * (float)((2 * r0 + 3) * k));
            F[p][k] = 0.5f * (a + b) * scale;
        }
    }
    __syncthreads();
    const int j = tid;
    float acc[8] = {0.f, 0.f, 0.f, 0.f, 0.f, 0.f, 0.f, 0.f};
    for (int k = 0; k < 25; ++k) {
        const float scale = (k == 0) ? sqrtf(1.0f / 256.0f) : sqrtf(2.0f / 256.0f);
        const float Dkj = cosf(c0 * (float)((2 * j + 1) * k)) * scale;
        #pragma unroll
        for (int p = 0; p < 8; ++p) acc[p] = fmaf(F[p][k], Dkj, acc[p]);
    }
    for (int p = 0; p < 8; ++p) E[p * 256 + j] = acc[p];
}

// Kernel 1: dct_in[img] = E * x[img] * E^T.  One block per image, 512 threads
// (two i-halves of 128 rows each to double wave count for latency hiding).
__global__ __launch_bounds__(512) void k_dct(const float* __restrict__ x,
                                             const float* __restrict__ Eg,
                                             float* __restrict__ dct_out) {
    __shared__ float El[8][257];
    __shared__ float T[8][257];
    const int img = blockIdx.x;
    const float* xi = x + (size_t)img * 65536;
    const int tid = threadIdx.x;
    const int j = tid & 255;
    const int half = tid >> 8;

    for (int idx = tid; idx < 2048; idx += 512) El[idx >> 8][idx & 255] = Eg[idx];
    __syncthreads();

    float t[8] = {0.f, 0.f, 0.f, 0.f, 0.f, 0.f, 0.f, 0.f};
    const int i0 = half * 128;
    for (int i = i0; i < i0 + 128; ++i) {
        const float v = xi[i * 256 + j];
        #pragma unroll
        for (int p = 0; p < 8; ++p) t[p] = fmaf(El[p][i], v, t[p]);
    }
    if (half == 0) {
        #pragma unroll
        for (int p = 0; p < 8; ++p) T[p][j] = t[p];
    }
    __syncthreads();
    if (half == 1) {
        #pragma unroll
        for (int p = 0; p < 8; ++p) T[p][j] += t[p];
    }
    __syncthreads();
    if (tid < 64) {
        const int p = tid >> 3, q = tid & 7;
        float s = 0.0f;
        for (int jj = 0; jj < 256; ++jj) s = fmaf(T[p][jj], El[q][jj], s);
        dct_out[img * 64 + tid] = s;
    }
}

// Kernel 2: grad_in[img,p,q] = 0.25 * sum of sobel magnitude at the 4 sampled
// pixels (rows/cols 32p+15,32p+16). Wrap never triggers (indices in [14,241]).
__global__ __launch_bounds__(64) void k_grad(const float* __restrict__ x,
                                             float* __restrict__ grad_out) {
    const int img = blockIdx.x;
    const int tid = threadIdx.x;            // 0..63
    const int p = tid >> 3, q = tid & 7;
    const float* xi = x + (size_t)img * 65536;
    const int r0 = 32 * p + 15, c0 = 32 * q + 15;
    float acc = 0.0f;
    #pragma unroll
    for (int dr = 0; dr < 2; ++dr) {
        #pragma unroll
        for (int dc = 0; dc < 2; ++dc) {
            const int r = r0 + dr, c = c0 + dc;
            const float a00 = xi[(r - 1) * 256 + (c - 1)];
            const float a01 = xi[(r - 1) * 256 + c];
            const float a02 = xi[(r - 1) * 256 + (c + 1)];
            const float a10 = xi[r * 256 + (c - 1)];
            const float a12 = xi[r * 256 + (c + 1)];
            const float a20 = xi[(r + 1) * 256 + (c - 1)];
            const float a21 = xi[(r + 1) * 256 + c];
            const float a22 = xi[(r + 1) * 256 + (c + 1)];
            const float gx = (a02 - a00) + 2.0f * (a12 - a10) + (a22 - a20);
            const float gy = (a20 - a00) + 2.0f * (a21 - a01) + (a22 - a02);
            acc += sqrtf(gx * gx + gy * gy);
        }
    }
    grad_out[img * 64 + tid] = 0.25f * acc;
}

// Kernel 3: conv3x3(3->64,pad1) + bias + BN + relu for both branches, mean,
// sigmoid gate, fuse, classifier. One block per batch item, 256 threads
// (64 c_out x 4 row-chunks of 2 rows each).
__global__ __launch_bounds__(256) void k_head(
    const float* __restrict__ dct_in, const float* __restrict__ grad_in,
    const float* __restrict__ wd, const float* __restrict__ bd,
    const float* __restrict__ gd, const float* __restrict__ betad,
    const float* __restrict__ wg, const float* __restrict__ bg,
    const float* __restrict__ gg, const float* __restrict__ betag,
    const float* __restrict__ fus_w, const float* __restrict__ fus_b,
    const float* __restrict__ cls_w, const float* __restrict__ cls_b,
    float* __restrict__ out) {
    __shared__ float ind[3][8][8];
    __shared__ float ing[3][8][8];
    __shared__ float wdl[1728];
    __shared__ float wgl[1728];
    __shared__ float redS[256];
    __shared__ float redF[64];
    __shared__ float redO0[256];
    __shared__ float redO1[256];
    __shared__ float wshare;

    const int b = blockIdx.x;
    const int tid = threadIdx.x;
    const int co = tid & 63;
    const int chunk = tid >> 6;

    float* pind = &ind[0][0][0];
    float* ping = &ing[0][0][0];
    for (int i = tid; i < 192; i += 256) {
        pind[i] = dct_in[b * 192 + i];
        ping[i] = grad_in[b * 192 + i];
    }
    for (int i = tid; i < 1728; i += 256) {
        wdl[i] = wd[i];
        wgl[i] = wg[i];
    }
    __syncthreads();

    const float scale_d = gd[co] / sqrtf(1.0f + 1e-5f);
    const float scale_g = gg[co] / sqrtf(1.0f + 1e-5f);
    const float beta_d = betad[co];
    const float beta_g = betag[co];
    const float bias_d = bd[co];
    const float bias_g = bg[co];

    float dreg[16], greg[16];
    float ssum = 0.0f;
    int idx = 0;
    for (int pr = chunk * 2; pr < chunk * 2 + 2; ++pr) {
        for (int qc = 0; qc < 8; ++qc) {
            float sd = bias_d, sg = bias_g;
            for (int ci = 0; ci < 3; ++ci) {
                #pragma unroll
                for (int du = 0; du < 3; ++du) {
                    const int r = pr + du - 1;
                    if (r < 0 || r > 7) continue;
                    #pragma unroll
                    for (int dv = 0; dv < 3; ++dv) {
                        const int c = qc + dv - 1;
                        if (c < 0 || c > 7) continue;
                        const float wv_d = wdl[co * 27 + ci * 9 + du * 3 + dv];
                        const float wv_g = wgl[co * 27 + ci * 9 + du * 3 + dv];
                        sd = fmaf(wv_d, ind[ci][r][c], sd);
                        sg = fmaf(wv_g, ing[ci][r][c], sg);
                    }
                }
            }
            sd = fmaxf(sd * scale_d + beta_d, 0.0f);
            sg = fmaxf(sg * scale_g + beta_g, 0.0f);
            dreg[idx] = sd;
            greg[idx] = sg;
            ssum += sd + sg;
            ++idx;
        }
    }

    redS[tid] = ssum;
    __syncthreads();
    if (tid < 64) {
        const float s =
            (redS[co] + redS[64 + co] + redS[128 + co] + redS[192 + co]) *
            (1.0f / 64.0f);
        redF[co] = s * fus_w[co];
    }
    __syncthreads();
    if (tid == 0) {
        float z = fus_b[0];
        for (int i = 0; i < 64; ++i) z += redF[i];
        wshare = 1.0f / (1.0f + expf(-z));
    }
    __syncthreads();
    const float wgt = wshare;

    float po0 = 0.0f, po1 = 0.0f;
    idx = 0;
    for (int pr = chunk * 2; pr < chunk * 2 + 2; ++pr) {
        for (int qc = 0; qc < 8; ++qc) {
            const float f = wgt * dreg[idx] + (1.0f - wgt) * greg[idx];
            const int n = co * 64 + pr * 8 + qc;
            po0 = fmaf(f, cls_w[n], po0);
            po1 = fmaf(f, cls_w[4096 + n], po1);
            ++idx;
        }
    }
    redO0[tid] = po0;
    redO1[tid] = po1;
    __syncthreads();
    if (tid < 64) {
        redO0[tid] += redO0[tid + 64] + redO0[tid + 128] + redO0[tid + 192];
        redO1[tid] += redO1[tid + 64] + redO1[tid + 128] + redO1[tid + 192];
    }
    __syncthreads();
    if (tid == 0) {
        float s = cls_b[0];
        for (int i = 0; i < 64; ++i) s += redO0[i];
        out[b * 2 + 0] = s;
    }
    if (tid == 1) {
        float s = cls_b[1];
        for (int i = 0; i < 64; ++i) s += redO1[i];
        out[b * 2 + 1] = s;
    }
}

extern "C" void kernel_launch(void* const* d_in, const int* in_sizes, int n_in,
                              void* d_out, int out_size, void* d_ws, size_t ws_size,
                              hipStream_t stream) {
    const float* x     = (const float*)d_in[0];
    const float* wd    = (const float*)d_in[1];
    const float* bd    = (const float*)d_in[2];
    const float* gd    = (const float*)d_in[3];
    const float* betad = (const float*)d_in[4];
    const float* wg    = (const float*)d_in[5];
    const float* bg    = (const float*)d_in[6];
    const float* gg    = (const float*)d_in[7];
    const float* betag = (const float*)d_in[8];
    const float* fusw  = (const float*)d_in[9];
    const float* fusb  = (const float*)d_in[10];
    const float* clsw  = (const float*)d_in[11];
    const float* clsb  = (const float*)d_in[12];
    float* out = (float*)d_out;

    float* ws = (float*)d_ws;
    float* E       = ws;                  // 8*256   = 2048 floats
    float* dct_in  = ws + 2048;           // 384*64  = 24576 floats
    float* grad_in = ws + 2048 + 24576;   // 384*64  = 24576 floats

    k_compute_E<<<1, 256, 0, stream>>>(E);
    k_grad<<<384, 64, 0, stream>>>(x, grad_in);
    k_dct<<<384, 512, 0, stream>>>(x, E, dct_in);
    k_head<<<128, 256, 0, stream>>>(dct_in, grad_in, wd, bd, gd, betad,
                                    wg, bg, gg, betag, fusw, fusb, clsw, clsb,
                                    out);
}

// Round 2
// 196.954 us; speedup vs baseline: 1.0322x; 1.0322x over previous
//
#include <hip/hip_runtime.h>
#include <math.h>

// ---------------------------------------------------------------------------
// AdaptiveFusionNet:
//   dct_in[b,c] = E x[b,c] E^T   (E = resize8 @ idct @ keep25 @ dct, 8x256)
//   grad_in[b,c,p,q] = avg of sobel magnitude at the 4 bilinear sample pixels
//   head: conv3x3(3->64)+bias+BN+relu (x2), mean, sigmoid gate, fuse, linear
// ---------------------------------------------------------------------------

// Kernel 0: Et[j][p] = E[p][j] = sum_{k<25} F[p,k] * D[k,j]
// F[p,k] = 0.5*(D[k,32p+15]+D[k,32p+16])
// D[k,n] = cos( fl(fl(pi_f*(2n+1))*k) / 512 ) * scale_k   (match JAX fp32 path)
__global__ __launch_bounds__(256) void k_compute_Et(float* __restrict__ Et) {
    __shared__ float F[8][25];
    const int tid = threadIdx.x;
    const float pi_f = 3.14159274101257324f;  // float(pi), as JAX casts it
    if (tid < 25) {
        const int k = tid;
        const float scale = (k == 0) ? sqrtf(1.0f / 256.0f) : sqrtf(2.0f / 256.0f);
        for (int p = 0; p < 8; ++p) {
            const int n0 = 32 * p + 15;
            const float a0 = (pi_f * (float)(2 * n0 + 1)) * (float)k / 512.0f;
            const float a1 = (pi_f * (float)(2 * n0 + 3)) * (float)k / 512.0f;
            F[p][k] = 0.5f * (cosf(a0) + cosf(a1)) * scale;
        }
    }
    __syncthreads();
    const int j = tid;
    float acc[8] = {0.f, 0.f, 0.f, 0.f, 0.f, 0.f, 0.f, 0.f};
    for (int k = 0; k < 25; ++k) {
        const float scale = (k == 0) ? sqrtf(1.0f / 256.0f) : sqrtf(2.0f / 256.0f);
        const float arg = (pi_f * (float)(2 * j + 1)) * (float)k / 512.0f;
        const float Dkj = cosf(arg) * scale;
        #pragma unroll
        for (int p = 0; p < 8; ++p) acc[p] = fmaf(F[p][k], Dkj, acc[p]);
    }
    #pragma unroll
    for (int p = 0; p < 8; ++p) Et[j * 8 + p] = acc[p];
}

// Kernel 1: one block per image (512 thr = 8 waves).
// Wave w: row-chunk cw=w>>1 (64 rows), column-half ch=w&1 (128 cols).
// Lane l owns 2 columns (float2). E-row read = 2 broadcast ds_read_b128.
__global__ __launch_bounds__(512) void k_dct(const float* __restrict__ x,
                                             const float* __restrict__ Etg,
                                             float* __restrict__ dct_out) {
    __shared__ float Et[256][8];   // Et[j][p] = E[p][j]        (8 KB)
    __shared__ float T[8][256];    // row-stage result          (8 KB)
    __shared__ float PO[8][64];    // epilogue partials         (2 KB)

    const int img = blockIdx.x;
    const float* xi = x + (size_t)img * 65536;
    const int tid = threadIdx.x;

    float* etf = &Et[0][0];
    for (int i = tid; i < 2048; i += 512) etf[i] = Etg[i];
    __syncthreads();

    const int w = tid >> 6, l = tid & 63;
    const int cw = w >> 1, ch = w & 1;
    const int col = ch * 128 + 2 * l;

    float acc[8][2];
    #pragma unroll
    for (int p = 0; p < 8; ++p) { acc[p][0] = 0.f; acc[p][1] = 0.f; }

    const float* px = xi + (size_t)(cw * 64) * 256 + col;
    #pragma unroll 4
    for (int i = 0; i < 64; ++i) {
        const float2 v = *(const float2*)px;
        px += 256;
        const int row = cw * 64 + i;
        const float4 ea = *(const float4*)&Et[row][0];
        const float4 eb = *(const float4*)&Et[row][4];
        acc[0][0] = fmaf(ea.x, v.x, acc[0][0]); acc[0][1] = fmaf(ea.x, v.y, acc[0][1]);
        acc[1][0] = fmaf(ea.y, v.x, acc[1][0]); acc[1][1] = fmaf(ea.y, v.y, acc[1][1]);
        acc[2][0] = fmaf(ea.z, v.x, acc[2][0]); acc[2][1] = fmaf(ea.z, v.y, acc[2][1]);
        acc[3][0] = fmaf(ea.w, v.x, acc[3][0]); acc[3][1] = fmaf(ea.w, v.y, acc[3][1]);
        acc[4][0] = fmaf(eb.x, v.x, acc[4][0]); acc[4][1] = fmaf(eb.x, v.y, acc[4][1]);
        acc[5][0] = fmaf(eb.y, v.x, acc[5][0]); acc[5][1] = fmaf(eb.y, v.y, acc[5][1]);
        acc[6][0] = fmaf(eb.z, v.x, acc[6][0]); acc[6][1] = fmaf(eb.z, v.y, acc[6][1]);
        acc[7][0] = fmaf(eb.w, v.x, acc[7][0]); acc[7][1] = fmaf(eb.w, v.y, acc[7][1]);
    }

    // Accumulate the 4 row-chunk partials into T (chunk order = ascending i).
    // Per round, the 2 active waves (ch=0/1) write disjoint column halves.
    for (int r = 0; r < 4; ++r) {
        if (cw == r) {
            if (r == 0) {
                #pragma unroll
                for (int p = 0; p < 8; ++p) {
                    float2 t; t.x = acc[p][0]; t.y = acc[p][1];
                    *(float2*)&T[p][col] = t;
                }
            } else {
                #pragma unroll
                for (int p = 0; p < 8; ++p) {
                    float2 t = *(const float2*)&T[p][col];
                    t.x += acc[p][0]; t.y += acc[p][1];
                    *(float2*)&T[p][col] = t;
                }
            }
        }
        __syncthreads();
    }

    // Column stage: out[p][q] = sum_j T[p][j] * Et[j][q], all 512 threads.
    const int pq = tid & 63, seg = tid >> 6;
    const int p = pq >> 3, q = pq & 7;
    float s = 0.0f;
    const int j0 = seg * 32;
    for (int j = j0; j < j0 + 32; ++j) s = fmaf(T[p][j], Et[j][q], s);
    PO[seg][pq] = s;
    __syncthreads();
    if (tid < 64) {
        float r = PO[0][tid] + PO[1][tid] + PO[2][tid] + PO[3][tid] +
                  PO[4][tid] + PO[5][tid] + PO[6][tid] + PO[7][tid];
        dct_out[img * 64 + tid] = r;
    }
}

// Kernel 2: 256 thr/img; tid = pq*4 + s, s = dr*2+dc picks one of the 4
// bilinear samples; shfl_xor reduce. Wrap never triggers (rows/cols 14..241).
__global__ __launch_bounds__(256) void k_grad(const float* __restrict__ x,
                                              float* __restrict__ grad_out) {
    const int img = blockIdx.x;
    const int tid = threadIdx.x;
    const int s = tid & 3, pq = tid >> 2;
    const int p = pq >> 3, q = pq & 7;
    const int dr = s >> 1, dc = s & 1;
    const float* xi = x + (size_t)img * 65536;
    const int r = 32 * p + 15 + dr, c = 32 * q + 15 + dc;
    const float* base = xi + (r - 1) * 256 + (c - 1);
    const float a00 = base[0],   a01 = base[1],   a02 = base[2];
    const float a10 = base[256],                  a12 = base[258];
    const float a20 = base[512], a21 = base[513], a22 = base[514];
    const float gx = (a02 - a00) + 2.0f * (a12 - a10) + (a22 - a20);
    const float gy = (a20 - a00) + 2.0f * (a21 - a01) + (a22 - a02);
    float m = sqrtf(gx * gx + gy * gy);
    m += __shfl_xor(m, 1);
    m += __shfl_xor(m, 2);
    if (s == 0) grad_out[img * 64 + pq] = 0.25f * m;
}

// Kernel 3: conv3x3(3->64,pad1)+bias+BN+relu both branches, mean, sigmoid
// gate, fuse, classifier. One block per batch item, 256 threads.
__global__ __launch_bounds__(256) void k_head(
    const float* __restrict__ dct_in, const float* __restrict__ grad_in,
    const float* __restrict__ wd, const float* __restrict__ bd,
    const float* __restrict__ gd, const float* __restrict__ betad,
    const float* __restrict__ wg, const float* __restrict__ bg,
    const float* __restrict__ gg, const float* __restrict__ betag,
    const float* __restrict__ fus_w, const float* __restrict__ fus_b,
    const float* __restrict__ cls_w, const float* __restrict__ cls_b,
    float* __restrict__ out) {
    __shared__ float ind[3][8][8];
    __shared__ float ing[3][8][8];
    __shared__ float wdl[1728];
    __shared__ float wgl[1728];
    __shared__ float redS[256];
    __shared__ float redF[64];
    __shared__ float redO0[256];
    __shared__ float redO1[256];
    __shared__ float wshare;

    const int b = blockIdx.x;
    const int tid = threadIdx.x;
    const int co = tid & 63;
    const int chunk = tid >> 6;

    float* pind = &ind[0][0][0];
    float* ping = &ing[0][0][0];
    for (int i = tid; i < 192; i += 256) {
        pind[i] = dct_in[b * 192 + i];
        ping[i] = grad_in[b * 192 + i];
    }
    for (int i = tid; i < 1728; i += 256) {
        wdl[i] = wd[i];
        wgl[i] = wg[i];
    }
    __syncthreads();

    const float scale_d = gd[co] / sqrtf(1.0f + 1e-5f);
    const float scale_g = gg[co] / sqrtf(1.0f + 1e-5f);
    const float beta_d = betad[co];
    const float beta_g = betag[co];
    const float bias_d = bd[co];
    const float bias_g = bg[co];

    float dreg[16], greg[16];
    float ssum = 0.0f;
    int idx = 0;
    for (int pr = chunk * 2; pr < chunk * 2 + 2; ++pr) {
        for (int qc = 0; qc < 8; ++qc) {
            float sd = bias_d, sg = bias_g;
            for (int ci = 0; ci < 3; ++ci) {
                #pragma unroll
                for (int du = 0; du < 3; ++du) {
                    const int r = pr + du - 1;
                    if (r < 0 || r > 7) continue;
                    #pragma unroll
                    for (int dv = 0; dv < 3; ++dv) {
                        const int c = qc + dv - 1;
                        if (c < 0 || c > 7) continue;
                        const float wv_d = wdl[co * 27 + ci * 9 + du * 3 + dv];
                        const float wv_g = wgl[co * 27 + ci * 9 + du * 3 + dv];
                        sd = fmaf(wv_d, ind[ci][r][c], sd);
                        sg = fmaf(wv_g, ing[ci][r][c], sg);
                    }
                }
            }
            sd = fmaxf(sd * scale_d + beta_d, 0.0f);
            sg = fmaxf(sg * scale_g + beta_g, 0.0f);
            dreg[idx] = sd;
            greg[idx] = sg;
            ssum += sd + sg;
            ++idx;
        }
    }

    redS[tid] = ssum;
    __syncthreads();
    if (tid < 64) {
        const float s =
            (redS[co] + redS[64 + co] + redS[128 + co] + redS[192 + co]) *
            (1.0f / 64.0f);
        redF[co] = s * fus_w[co];
    }
    __syncthreads();
    if (tid == 0) {
        float z = fus_b[0];
        for (int i = 0; i < 64; ++i) z += redF[i];
        wshare = 1.0f / (1.0f + expf(-z));
    }
    __syncthreads();
    const float wgt = wshare;

    float po0 = 0.0f, po1 = 0.0f;
    idx = 0;
    for (int pr = chunk * 2; pr < chunk * 2 + 2; ++pr) {
        for (int qc = 0; qc < 8; ++qc) {
            const float f = wgt * dreg[idx] + (1.0f - wgt) * greg[idx];
            const int n = co * 64 + pr * 8 + qc;
            po0 = fmaf(f, cls_w[n], po0);
            po1 = fmaf(f, cls_w[4096 + n], po1);
            ++idx;
        }
    }
    redO0[tid] = po0;
    redO1[tid] = po1;
    __syncthreads();
    if (tid < 64) {
        redO0[tid] += redO0[tid + 64] + redO0[tid + 128] + redO0[tid + 192];
        redO1[tid] += redO1[tid + 64] + redO1[tid + 128] + redO1[tid + 192];
    }
    __syncthreads();
    if (tid == 0) {
        float s = cls_b[0];
        for (int i = 0; i < 64; ++i) s += redO0[i];
        out[b * 2 + 0] = s;
    }
    if (tid == 1) {
        float s = cls_b[1];
        for (int i = 0; i < 64; ++i) s += redO1[i];
        out[b * 2 + 1] = s;
    }
}

extern "C" void kernel_launch(void* const* d_in, const int* in_sizes, int n_in,
                              void* d_out, int out_size, void* d_ws, size_t ws_size,
                              hipStream_t stream) {
    const float* x     = (const float*)d_in[0];
    const float* wd    = (const float*)d_in[1];
    const float* bd    = (const float*)d_in[2];
    const float* gd    = (const float*)d_in[3];
    const float* betad = (const float*)d_in[4];
    const float* wg    = (const float*)d_in[5];
    const float* bg    = (const float*)d_in[6];
    const float* gg    = (const float*)d_in[7];
    const float* betag = (const float*)d_in[8];
    const float* fusw  = (const float*)d_in[9];
    const float* fusb  = (const float*)d_in[10];
    const float* clsw  = (const float*)d_in[11];
    const float* clsb  = (const float*)d_in[12];
    float* out = (float*)d_out;

    float* ws = (float*)d_ws;
    float* Et      = ws;                  // 256*8  = 2048 floats
    float* dct_in  = ws + 2048;           // 384*64 = 24576 floats
    float* grad_in = ws + 2048 + 24576;   // 384*64 = 24576 floats

    k_compute_Et<<<1, 256, 0, stream>>>(Et);
    k_grad<<<384, 256, 0, stream>>>(x, grad_in);
    k_dct<<<384, 512, 0, stream>>>(x, Et, dct_in);
    k_head<<<128, 256, 0, stream>>>(dct_in, grad_in, wd, bd, gd, betad,
                                    wg, bg, gg, betag, fusw, fusb, clsw, clsb,
                                    out);
}

// Round 3
// 189.319 us; speedup vs baseline: 1.0738x; 1.0403x over previous
//
#include <hip/hip_runtime.h>
#include <math.h>

// ---------------------------------------------------------------------------
// AdaptiveFusionNet, 2 kernels:
//  k_main (1 block/image): Et = (resize8@idct@keep25@dct)^T computed in-block,
//    dct_in = E x E^T, grad_in = 4-sample sobel magnitude (fused, phase A).
//  k_head (1 block/batch): conv3x3(3->64)+bias+BN+relu x2, mean, sigmoid
//    gate, fuse, classifier (coalesced via LDS-staged features).
// ---------------------------------------------------------------------------

__global__ __launch_bounds__(512) void k_main(const float* __restrict__ x,
                                              float* __restrict__ dct_out,
                                              float* __restrict__ grad_out) {
    __shared__ float F[8][25];
    __shared__ float Et[256][8];   // Et[j][p] = E[p][j]
    __shared__ float T[8][256];
    __shared__ float PO[8][64];

    const int img = blockIdx.x;
    const float* xi = x + (size_t)img * 65536;
    const int tid = threadIdx.x;
    const float pi_f = 3.14159274101257324f;  // float(pi), JAX fp32 path

    // --- phase A: waves 4..7 do the sobel/grad samples; lane<25 of wave 0
    //     builds F. (No barriers inside either side.)
    if (tid >= 256) {
        const int t = tid - 256;
        const int s = t & 3, pq = t >> 2;
        const int p = pq >> 3, q = pq & 7;
        const int dr = s >> 1, dc = s & 1;
        const int r = 32 * p + 15 + dr, c = 32 * q + 15 + dc;  // 14..241
        const float* base = xi + (r - 1) * 256 + (c - 1);
        const float a00 = base[0],   a01 = base[1],   a02 = base[2];
        const float a10 = base[256],                  a12 = base[258];
        const float a20 = base[512], a21 = base[513], a22 = base[514];
        const float gx = (a02 - a00) + 2.0f * (a12 - a10) + (a22 - a20);
        const float gy = (a20 - a00) + 2.0f * (a21 - a01) + (a22 - a02);
        float m = sqrtf(gx * gx + gy * gy);
        m += __shfl_xor(m, 1);
        m += __shfl_xor(m, 2);
        if (s == 0) grad_out[img * 64 + pq] = 0.25f * m;
    } else if (tid < 25) {
        const int k = tid;
        const float scale = (k == 0) ? sqrtf(1.0f / 256.0f) : sqrtf(2.0f / 256.0f);
        for (int p = 0; p < 8; ++p) {
            const int n0 = 32 * p + 15;
            const float a0 = (pi_f * (float)(2 * n0 + 1)) * (float)k / 512.0f;
            const float a1 = (pi_f * (float)(2 * n0 + 3)) * (float)k / 512.0f;
            F[p][k] = 0.5f * (cosf(a0) + cosf(a1)) * scale;
        }
    }
    __syncthreads();

    // --- Et row j (threads 0..255)
    if (tid < 256) {
        const int j = tid;
        float acc[8] = {0.f, 0.f, 0.f, 0.f, 0.f, 0.f, 0.f, 0.f};
        for (int k = 0; k < 25; ++k) {
            const float scale = (k == 0) ? sqrtf(1.0f / 256.0f) : sqrtf(2.0f / 256.0f);
            const float arg = (pi_f * (float)(2 * j + 1)) * (float)k / 512.0f;
            const float Dkj = cosf(arg) * scale;
            #pragma unroll
            for (int p = 0; p < 8; ++p) acc[p] = fmaf(F[p][k], Dkj, acc[p]);
        }
        #pragma unroll
        for (int p = 0; p < 8; ++p) Et[j][p] = acc[p];
    }
    __syncthreads();

    // --- row stage: wave w: cw=w>>1 (64-row chunk), ch=w&1 (128-col half),
    //     lane owns 2 cols (float2 loads). Et row read = 2 broadcast b128.
    const int w = tid >> 6, l = tid & 63;
    const int cw = w >> 1, ch = w & 1;
    const int col = ch * 128 + 2 * l;

    float acc[8][2];
    #pragma unroll
    for (int p = 0; p < 8; ++p) { acc[p][0] = 0.f; acc[p][1] = 0.f; }

    const float* px = xi + (size_t)(cw * 64) * 256 + col;
    #pragma unroll 4
    for (int i = 0; i < 64; ++i) {
        const float2 v = *(const float2*)px;
        px += 256;
        const int row = cw * 64 + i;
        const float4 ea = *(const float4*)&Et[row][0];
        const float4 eb = *(const float4*)&Et[row][4];
        acc[0][0] = fmaf(ea.x, v.x, acc[0][0]); acc[0][1] = fmaf(ea.x, v.y, acc[0][1]);
        acc[1][0] = fmaf(ea.y, v.x, acc[1][0]); acc[1][1] = fmaf(ea.y, v.y, acc[1][1]);
        acc[2][0] = fmaf(ea.z, v.x, acc[2][0]); acc[2][1] = fmaf(ea.z, v.y, acc[2][1]);
        acc[3][0] = fmaf(ea.w, v.x, acc[3][0]); acc[3][1] = fmaf(ea.w, v.y, acc[3][1]);
        acc[4][0] = fmaf(eb.x, v.x, acc[4][0]); acc[4][1] = fmaf(eb.x, v.y, acc[4][1]);
        acc[5][0] = fmaf(eb.y, v.x, acc[5][0]); acc[5][1] = fmaf(eb.y, v.y, acc[5][1]);
        acc[6][0] = fmaf(eb.z, v.x, acc[6][0]); acc[6][1] = fmaf(eb.z, v.y, acc[6][1]);
        acc[7][0] = fmaf(eb.w, v.x, acc[7][0]); acc[7][1] = fmaf(eb.w, v.y, acc[7][1]);
    }

    // accumulate 4 row-chunk partials into T (2 active waves per round,
    // disjoint column halves)
    for (int r = 0; r < 4; ++r) {
        if (cw == r) {
            if (r == 0) {
                #pragma unroll
                for (int p = 0; p < 8; ++p) {
                    float2 t; t.x = acc[p][0]; t.y = acc[p][1];
                    *(float2*)&T[p][col] = t;
                }
            } else {
                #pragma unroll
                for (int p = 0; p < 8; ++p) {
                    float2 t = *(const float2*)&T[p][col];
                    t.x += acc[p][0]; t.y += acc[p][1];
                    *(float2*)&T[p][col] = t;
                }
            }
        }
        __syncthreads();
    }

    // column stage: out[p][q] = sum_j T[p][j]*Et[j][q]
    const int pq = tid & 63, seg = tid >> 6;
    const int p = pq >> 3, q = pq & 7;
    float s = 0.0f;
    const int j0 = seg * 32;
    for (int j = j0; j < j0 + 32; ++j) s = fmaf(T[p][j], Et[j][q], s);
    PO[seg][pq] = s;
    __syncthreads();
    if (tid < 64) {
        float r = PO[0][tid] + PO[1][tid] + PO[2][tid] + PO[3][tid] +
                  PO[4][tid] + PO[5][tid] + PO[6][tid] + PO[7][tid];
        dct_out[img * 64 + tid] = r;
    }
}

__global__ __launch_bounds__(256) void k_head(
    const float* __restrict__ dct_in, const float* __restrict__ grad_in,
    const float* __restrict__ wd, const float* __restrict__ bd,
    const float* __restrict__ gd, const float* __restrict__ betad,
    const float* __restrict__ wg, const float* __restrict__ bg,
    const float* __restrict__ gg, const float* __restrict__ betag,
    const float* __restrict__ fus_w, const float* __restrict__ fus_b,
    const float* __restrict__ cls_w, const float* __restrict__ cls_b,
    float* __restrict__ out) {
    __shared__ float ind[3][8][8];
    __shared__ float ing[3][8][8];
    __shared__ float wdl[1728];
    __shared__ float wgl[1728];
    __shared__ float redS[256];
    __shared__ float redF[64];
    __shared__ float fusedS[64][65];
    __shared__ float redW0[4];
    __shared__ float redW1[4];
    __shared__ float wshare;

    const int b = blockIdx.x;
    const int tid = threadIdx.x;
    const int co = tid & 63;
    const int chunk = tid >> 6;

    float* pind = &ind[0][0][0];
    float* ping = &ing[0][0][0];
    for (int i = tid; i < 192; i += 256) {
        pind[i] = dct_in[b * 192 + i];
        ping[i] = grad_in[b * 192 + i];
    }
    for (int i = tid; i < 1728; i += 256) {
        wdl[i] = wd[i];
        wgl[i] = wg[i];
    }
    __syncthreads();

    const float scale_d = gd[co] / sqrtf(1.0f + 1e-5f);
    const float scale_g = gg[co] / sqrtf(1.0f + 1e-5f);
    const float beta_d = betad[co];
    const float beta_g = betag[co];
    const float bias_d = bd[co];
    const float bias_g = bg[co];

    float dreg[16], greg[16];
    float ssum = 0.0f;
    int idx = 0;
    for (int pr = chunk * 2; pr < chunk * 2 + 2; ++pr) {
        for (int qc = 0; qc < 8; ++qc) {
            float sd = bias_d, sg = bias_g;
            for (int ci = 0; ci < 3; ++ci) {
                #pragma unroll
                for (int du = 0; du < 3; ++du) {
                    const int r = pr + du - 1;
                    if (r < 0 || r > 7) continue;
                    #pragma unroll
                    for (int dv = 0; dv < 3; ++dv) {
                        const int c = qc + dv - 1;
                        if (c < 0 || c > 7) continue;
                        const float wv_d = wdl[co * 27 + ci * 9 + du * 3 + dv];
                        const float wv_g = wgl[co * 27 + ci * 9 + du * 3 + dv];
                        sd = fmaf(wv_d, ind[ci][r][c], sd);
                        sg = fmaf(wv_g, ing[ci][r][c], sg);
                    }
                }
            }
            sd = fmaxf(sd * scale_d + beta_d, 0.0f);
            sg = fmaxf(sg * scale_g + beta_g, 0.0f);
            dreg[idx] = sd;
            greg[idx] = sg;
            ssum += sd + sg;
            ++idx;
        }
    }

    redS[tid] = ssum;
    __syncthreads();
    if (tid < 64) {
        const float s =
            (redS[co] + redS[64 + co] + redS[128 + co] + redS[192 + co]) *
            (1.0f / 64.0f);
        redF[co] = s * fus_w[co];
    }
    __syncthreads();
    if (tid < 64) {  // wave 0
        float v = redF[tid];
        #pragma unroll
        for (int off = 1; off < 64; off <<= 1) v += __shfl_xor(v, off);
        if (tid == 0) wshare = 1.0f / (1.0f + expf(-(v + fus_b[0])));
    }
    __syncthreads();
    const float wgt = wshare;

    // stage fused features: fusedS[co][pos], pos = chunk*16 + idx
    idx = 0;
    for (int pr = chunk * 2; pr < chunk * 2 + 2; ++pr) {
        for (int qc = 0; qc < 8; ++qc) {
            const float f = wgt * dreg[idx] + (1.0f - wgt) * greg[idx];
            fusedS[co][pr * 8 + qc] = f;
            ++idx;
        }
    }
    __syncthreads();

    // classifier: lane-consecutive n -> coalesced cls_w, conflict-free LDS
    const int l = tid & 63, wv = tid >> 6;
    float a0 = 0.0f, a1 = 0.0f;
    #pragma unroll
    for (int k = 0; k < 16; ++k) {
        const int n = tid + 256 * k;            // co = wv+4k, pos = l
        const float f = fusedS[wv + 4 * k][l];
        a0 = fmaf(f, cls_w[n], a0);
        a1 = fmaf(f, cls_w[4096 + n], a1);
    }
    #pragma unroll
    for (int off = 1; off < 64; off <<= 1) {
        a0 += __shfl_xor(a0, off);
        a1 += __shfl_xor(a1, off);
    }
    if (l == 0) { redW0[wv] = a0; redW1[wv] = a1; }
    __syncthreads();
    if (tid == 0) out[b * 2 + 0] = cls_b[0] + redW0[0] + redW0[1] + redW0[2] + redW0[3];
    if (tid == 1) out[b * 2 + 1] = cls_b[1] + redW1[0] + redW1[1] + redW1[2] + redW1[3];
}

extern "C" void kernel_launch(void* const* d_in, const int* in_sizes, int n_in,
                              void* d_out, int out_size, void* d_ws, size_t ws_size,
                              hipStream_t stream) {
    const float* x     = (const float*)d_in[0];
    const float* wd    = (const float*)d_in[1];
    const float* bd    = (const float*)d_in[2];
    const float* gd    = (const float*)d_in[3];
    const float* betad = (const float*)d_in[4];
    const float* wg    = (const float*)d_in[5];
    const float* bg    = (const float*)d_in[6];
    const float* gg    = (const float*)d_in[7];
    const float* betag = (const float*)d_in[8];
    const float* fusw  = (const float*)d_in[9];
    const float* fusb  = (const float*)d_in[10];
    const float* clsw  = (const float*)d_in[11];
    const float* clsb  = (const float*)d_in[12];
    float* out = (float*)d_out;

    float* ws = (float*)d_ws;
    float* dct_in  = ws;                  // 384*64 floats
    float* grad_in = ws + 24576;          // 384*64 floats

    k_main<<<384, 512, 0, stream>>>(x, dct_in, grad_in);
    k_head<<<128, 256, 0, stream>>>(dct_in, grad_in, wd, bd, gd, betad,
                                    wg, bg, gg, betag, fusw, fusb, clsw, clsb,
                                    out);
}

// Round 4
// 188.165 us; speedup vs baseline: 1.0804x; 1.0061x over previous
//
#include <hip/hip_runtime.h>
#include <math.h>

// ---------------------------------------------------------------------------
// AdaptiveFusionNet, 2 kernels:
//  k_main: grid 768 = 2 half-image blocks x 384 images, 256 thr (3 blocks/CU,
//    perfectly balanced). Each block: Et in-block, grad samples for its own
//    half, row-stage over its 128 rows (float4 loads), column stage on its
//    partial T -> dct_part[img][half][64]. Halves summed in k_head (linear).
//  k_head: conv3x3(3->64)+bias+BN+relu x2, mean, sigmoid gate, fuse,
//    classifier (coalesced cls_w, LDS-staged features).
// ---------------------------------------------------------------------------

__global__ __launch_bounds__(256) void k_main(const float* __restrict__ x,
                                              float* __restrict__ dct_part,
                                              float* __restrict__ grad_out) {
    __shared__ float F[8][25];
    __shared__ float Et[256][8];   // Et[j][p] = E[p][j]
    __shared__ float T[8][260];    // +4 pad: col-stage banks (4p+j)%32 distinct
    __shared__ float PO[4][64];

    const int bid = blockIdx.x;
    const int img = bid >> 1, half = bid & 1;
    const float* xi = x + (size_t)img * 65536;
    const int tid = threadIdx.x;
    const float pi_f = 3.14159274101257324f;  // float(pi), JAX fp32 path

    // --- phase A: waves 2..3 do this half's sobel/grad samples; lanes <25 of
    //     wave 0 build F. (No barriers inside either side.)
    if (tid >= 128) {
        const int t = tid - 128;
        const int s = t & 3, pq = t >> 2;        // pq 0..31
        const int pp = pq >> 3, q = pq & 7;
        const int p = half * 4 + pp;
        const int dr = s >> 1, dc = s & 1;
        const int r = 32 * p + 15 + dr, c = 32 * q + 15 + dc;  // 14..241
        const float* base = xi + (r - 1) * 256 + (c - 1);
        const float a00 = base[0],   a01 = base[1],   a02 = base[2];
        const float a10 = base[256],                  a12 = base[258];
        const float a20 = base[512], a21 = base[513], a22 = base[514];
        const float gx = (a02 - a00) + 2.0f * (a12 - a10) + (a22 - a20);
        const float gy = (a20 - a00) + 2.0f * (a21 - a01) + (a22 - a02);
        float m = sqrtf(gx * gx + gy * gy);
        m += __shfl_xor(m, 1);
        m += __shfl_xor(m, 2);
        if (s == 0) grad_out[img * 64 + p * 8 + q] = 0.25f * m;
    } else if (tid < 25) {
        const int k = tid;
        const float scale = (k == 0) ? sqrtf(1.0f / 256.0f) : sqrtf(2.0f / 256.0f);
        for (int p = 0; p < 8; ++p) {
            const int n0 = 32 * p + 15;
            const float a0 = (pi_f * (float)(2 * n0 + 1)) * (float)k / 512.0f;
            const float a1 = (pi_f * (float)(2 * n0 + 3)) * (float)k / 512.0f;
            F[p][k] = 0.5f * (cosf(a0) + cosf(a1)) * scale;
        }
    }
    __syncthreads();

    // --- Et row j = tid (all 256 threads)
    {
        const int j = tid;
        float acc[8] = {0.f, 0.f, 0.f, 0.f, 0.f, 0.f, 0.f, 0.f};
        for (int k = 0; k < 25; ++k) {
            const float scale = (k == 0) ? sqrtf(1.0f / 256.0f) : sqrtf(2.0f / 256.0f);
            const float arg = (pi_f * (float)(2 * j + 1)) * (float)k / 512.0f;
            const float Dkj = cosf(arg) * scale;
            #pragma unroll
            for (int p = 0; p < 8; ++p) acc[p] = fmaf(F[p][k], Dkj, acc[p]);
        }
        #pragma unroll
        for (int p = 0; p < 8; ++p) Et[j][p] = acc[p];
    }
    __syncthreads();

    // --- row stage: wave w handles 32 rows (ascending), lane owns 4 cols.
    const int w = tid >> 6, l = tid & 63;
    const int col = 4 * l;
    const int rbase = half * 128 + w * 32;

    float acc[8][4];
    #pragma unroll
    for (int p = 0; p < 8; ++p)
        #pragma unroll
        for (int c = 0; c < 4; ++c) acc[p][c] = 0.f;

    const float* px = xi + (size_t)rbase * 256 + col;
    #pragma unroll 4
    for (int i = 0; i < 32; ++i) {
        const float4 v = *(const float4*)px;
        px += 256;
        const int row = rbase + i;
        const float4 ea = *(const float4*)&Et[row][0];
        const float4 eb = *(const float4*)&Et[row][4];
        const float e[8] = {ea.x, ea.y, ea.z, ea.w, eb.x, eb.y, eb.z, eb.w};
        #pragma unroll
        for (int p = 0; p < 8; ++p) {
            acc[p][0] = fmaf(e[p], v.x, acc[p][0]);
            acc[p][1] = fmaf(e[p], v.y, acc[p][1]);
            acc[p][2] = fmaf(e[p], v.z, acc[p][2]);
            acc[p][3] = fmaf(e[p], v.w, acc[p][3]);
        }
    }

    // accumulate 4 wave partials into T in ascending-row order
    for (int r = 0; r < 4; ++r) {
        if (w == r) {
            if (r == 0) {
                #pragma unroll
                for (int p = 0; p < 8; ++p) {
                    float4 t;
                    t.x = acc[p][0]; t.y = acc[p][1];
                    t.z = acc[p][2]; t.w = acc[p][3];
                    *(float4*)&T[p][col] = t;
                }
            } else {
                #pragma unroll
                for (int p = 0; p < 8; ++p) {
                    float4 t = *(const float4*)&T[p][col];
                    t.x += acc[p][0]; t.y += acc[p][1];
                    t.z += acc[p][2]; t.w += acc[p][3];
                    *(float4*)&T[p][col] = t;
                }
            }
        }
        __syncthreads();
    }

    // column stage on this half's T: outp[p][q] = sum_j T[p][j]*Et[j][q]
    const int pq = tid & 63, seg = tid >> 6;
    const int p = pq >> 3, q = pq & 7;
    float s = 0.0f;
    const int j0 = seg * 64;
    for (int j = j0; j < j0 + 64; ++j) s = fmaf(T[p][j], Et[j][q], s);
    PO[seg][pq] = s;
    __syncthreads();
    if (tid < 64) {
        const float r4 = PO[0][tid] + PO[1][tid] + PO[2][tid] + PO[3][tid];
        dct_part[img * 128 + half * 64 + tid] = r4;
    }
}

__global__ __launch_bounds__(256) void k_head(
    const float* __restrict__ dct_part, const float* __restrict__ grad_in,
    const float* __restrict__ wd, const float* __restrict__ bd,
    const float* __restrict__ gd, const float* __restrict__ betad,
    const float* __restrict__ wg, const float* __restrict__ bg,
    const float* __restrict__ gg, const float* __restrict__ betag,
    const float* __restrict__ fus_w, const float* __restrict__ fus_b,
    const float* __restrict__ cls_w, const float* __restrict__ cls_b,
    float* __restrict__ out) {
    __shared__ float ind[3][8][8];
    __shared__ float ing[3][8][8];
    __shared__ float wdl[1728];
    __shared__ float wgl[1728];
    __shared__ float redS[256];
    __shared__ float redF[64];
    __shared__ float fusedS[64][65];
    __shared__ float redW0[4];
    __shared__ float redW1[4];
    __shared__ float wshare;

    const int b = blockIdx.x;
    const int tid = threadIdx.x;
    const int co = tid & 63;
    const int chunk = tid >> 6;

    float* pind = &ind[0][0][0];
    float* ping = &ing[0][0][0];
    for (int i = tid; i < 192; i += 256) {
        const int ci = i >> 6, pq = i & 63;
        const float* dp = dct_part + (size_t)(3 * b + ci) * 128;
        pind[i] = dp[pq] + dp[64 + pq];   // half0 + half1 (linear col stage)
        ping[i] = grad_in[b * 192 + i];
    }
    for (int i = tid; i < 1728; i += 256) {
        wdl[i] = wd[i];
        wgl[i] = wg[i];
    }
    __syncthreads();

    const float scale_d = gd[co] / sqrtf(1.0f + 1e-5f);
    const float scale_g = gg[co] / sqrtf(1.0f + 1e-5f);
    const float beta_d = betad[co];
    const float beta_g = betag[co];
    const float bias_d = bd[co];
    const float bias_g = bg[co];

    float dreg[16], greg[16];
    float ssum = 0.0f;
    int idx = 0;
    for (int pr = chunk * 2; pr < chunk * 2 + 2; ++pr) {
        for (int qc = 0; qc < 8; ++qc) {
            float sd = bias_d, sg = bias_g;
            for (int ci = 0; ci < 3; ++ci) {
                #pragma unroll
                for (int du = 0; du < 3; ++du) {
                    const int r = pr + du - 1;
                    if (r < 0 || r > 7) continue;
                    #pragma unroll
                    for (int dv = 0; dv < 3; ++dv) {
                        const int c = qc + dv - 1;
                        if (c < 0 || c > 7) continue;
                        const float wv_d = wdl[co * 27 + ci * 9 + du * 3 + dv];
                        const float wv_g = wgl[co * 27 + ci * 9 + du * 3 + dv];
                        sd = fmaf(wv_d, ind[ci][r][c], sd);
                        sg = fmaf(wv_g, ing[ci][r][c], sg);
                    }
                }
            }
            sd = fmaxf(sd * scale_d + beta_d, 0.0f);
            sg = fmaxf(sg * scale_g + beta_g, 0.0f);
            dreg[idx] = sd;
            greg[idx] = sg;
            ssum += sd + sg;
            ++idx;
        }
    }

    redS[tid] = ssum;
    __syncthreads();
    if (tid < 64) {
        const float s =
            (redS[co] + redS[64 + co] + redS[128 + co] + redS[192 + co]) *
            (1.0f / 64.0f);
        redF[co] = s * fus_w[co];
    }
    __syncthreads();
    if (tid < 64) {  // wave 0
        float v = redF[tid];
        #pragma unroll
        for (int off = 1; off < 64; off <<= 1) v += __shfl_xor(v, off);
        if (tid == 0) wshare = 1.0f / (1.0f + expf(-(v + fus_b[0])));
    }
    __syncthreads();
    const float wgt = wshare;

    // stage fused features: fusedS[co][pos]
    idx = 0;
    for (int pr = chunk * 2; pr < chunk * 2 + 2; ++pr) {
        for (int qc = 0; qc < 8; ++qc) {
            const float f = wgt * dreg[idx] + (1.0f - wgt) * greg[idx];
            fusedS[co][pr * 8 + qc] = f;
            ++idx;
        }
    }
    __syncthreads();

    // classifier: lane-consecutive n -> coalesced cls_w, conflict-free LDS
    const int l = tid & 63, wv = tid >> 6;
    float a0 = 0.0f, a1 = 0.0f;
    #pragma unroll
    for (int k = 0; k < 16; ++k) {
        const int n = tid + 256 * k;            // co = wv+4k, pos = l
        const float f = fusedS[wv + 4 * k][l];
        a0 = fmaf(f, cls_w[n], a0);
        a1 = fmaf(f, cls_w[4096 + n], a1);
    }
    #pragma unroll
    for (int off = 1; off < 64; off <<= 1) {
        a0 += __shfl_xor(a0, off);
        a1 += __shfl_xor(a1, off);
    }
    if (l == 0) { redW0[wv] = a0; redW1[wv] = a1; }
    __syncthreads();
    if (tid == 0) out[b * 2 + 0] = cls_b[0] + redW0[0] + redW0[1] + redW0[2] + redW0[3];
    if (tid == 1) out[b * 2 + 1] = cls_b[1] + redW1[0] + redW1[1] + redW1[2] + redW1[3];
}

extern "C" void kernel_launch(void* const* d_in, const int* in_sizes, int n_in,
                              void* d_out, int out_size, void* d_ws, size_t ws_size,
                              hipStream_t stream) {
    const float* x     = (const float*)d_in[0];
    const float* wd    = (const float*)d_in[1];
    const float* bd    = (const float*)d_in[2];
    const float* gd    = (const float*)d_in[3];
    const float* betad = (const float*)d_in[4];
    const float* wg    = (const float*)d_in[5];
    const float* bg    = (const float*)d_in[6];
    const float* gg    = (const float*)d_in[7];
    const float* betag = (const float*)d_in[8];
    const float* fusw  = (const float*)d_in[9];
    const float* fusb  = (const float*)d_in[10];
    const float* clsw  = (const float*)d_in[11];
    const float* clsb  = (const float*)d_in[12];
    float* out = (float*)d_out;

    float* ws = (float*)d_ws;
    float* dct_part = ws;                 // 384*128 = 49152 floats
    float* grad_in  = ws + 49152;         // 384*64  = 24576 floats

    k_main<<<768, 256, 0, stream>>>(x, dct_part, grad_in);
    k_head<<<128, 256, 0, stream>>>(dct_part, grad_in, wd, bd, gd, betad,
                                    wg, bg, gg, betag, fusw, fusb, clsw, clsb,
                                    out);
}